// Round 1
// baseline (378.245 us; speedup 1.0000x reference)
//
#include <hip/hip_runtime.h>

// FastIMDCT4: B=32, T=1024, n_fft=2048, hop=1024.
// Per (b,t): c[k] = tw[k]*(sig[2k] + i*sig[1023-2k]), k<512
//            c = fft_512(c); c = tw[k]*c
//            inter[2k]=Re(c[k]), inter[2k+1]=Im(c[k])
//            frames[m] = sign[m]*window[m]/512 * inter[post[m]], m<2048
// Overlap-add hop=1024 then trim 1024 each end:
//            out[b, q*1024+r] = frames[b,q,1024+r] + frames[b,q+1,r]
// One block per (b,q) computes both frames (dup compute, no atomics).

#define N4 512
#define N2 1024
#define CHUNKS 1023
#define OUTB (CHUNKS * 1024)

__device__ __forceinline__ float2 cmul(float2 a, float2 b) {
    return make_float2(a.x * b.x - a.y * b.y, a.x * b.y + a.y * b.x);
}

// post[] / sign[] closed forms (derived from reference _consts, spot-verified):
//   m in [0,512):     post = even ? m+512  : 512-m
//   m in [512,1536):  post = even ? m-511  : 1535-m
//   m in [1536,2048): post = even ? m-1536 : 2560-m
//   sign: m<1536: even?+1:-1 ; m>=1536: even?-1:+1
__device__ __forceinline__ void postmap(int m, int& p, float& sgn) {
    bool even = ((m & 1) == 0);
    if (m < 512)       p = even ? (m + 512)  : (512 - m);
    else if (m < 1536) p = even ? (m - 511)  : (1535 - m);
    else               p = even ? (m - 1536) : (2560 - m);
    float s1 = even ? 1.0f : -1.0f;
    sgn = (m < 1536) ? s1 : -s1;
}

__global__ __launch_bounds__(256) void imdct_kernel(
        const float* __restrict__ signal,
        const float* __restrict__ window,
        float* __restrict__ out) {
    __shared__ float2 X[N4];     // FFT working buffer (in-place)
    __shared__ float2 TW[N4];    // pre/post twiddle exp(-2pi i (k+0.125)/2048)
    __shared__ float2 W[256];    // FFT twiddles exp(-2pi i j/512)

    const int tid = threadIdx.x;
    const int bid = blockIdx.x;
    const int b = bid / CHUNKS;
    const int q = bid - b * CHUNKS;

    // Build twiddle tables once per block.
    for (int k = tid; k < N4; k += 256) {
        float ang = -6.283185307179586f * ((float)k + 0.125f) * (1.0f / 2048.0f);
        float s, c;
        sincosf(ang, &s, &c);
        TW[k] = make_float2(c, s);
    }
    {
        float ang = -6.283185307179586f * (float)tid * (1.0f / 512.0f);
        float s, c;
        sincosf(ang, &s, &c);
        W[tid] = make_float2(c, s);
    }
    __syncthreads();

    float acc[4];

    for (int half_sel = 0; half_sel < 2; ++half_sel) {
        // half_sel==0: frame q   -> need m in [1024,2048) (second half)
        // half_sel==1: frame q+1 -> need m in [0,1024)    (first half)
        const float* row = signal + ((size_t)(b * 1024 + q + half_sel)) * N2;

        // Load, pre-twiddle, bit-reverse scatter into X.
        for (int k = tid; k < N4; k += 256) {
            float re = row[2 * k];
            float im = row[1023 - 2 * k];
            float2 c = cmul(TW[k], make_float2(re, im));
            int br = __brev((unsigned)k) >> 23;  // 9-bit reversal
            X[br] = c;
        }
        __syncthreads();

        // In-place radix-2 DIT, 9 stages, 256 butterflies/stage (1/thread).
        #pragma unroll
        for (int s = 1; s <= 9; ++s) {
            int half = 1 << (s - 1);
            int pos = tid & (half - 1);
            int grp = tid >> (s - 1);
            int i0 = (grp << s) + pos;
            int i1 = i0 + half;
            float2 w = W[pos << (9 - s)];
            float2 a = X[i0];
            float2 bb = X[i1];
            float2 wb = cmul(w, bb);
            X[i0] = make_float2(a.x + wb.x, a.y + wb.y);
            X[i1] = make_float2(a.x - wb.x, a.y - wb.y);
            __syncthreads();
        }

        // Post-twiddle in place.
        for (int k = tid; k < N4; k += 256) {
            X[k] = cmul(TW[k], X[k]);
        }
        __syncthreads();

        // Extraction: inter[p] = (p even) ? Re(c[p/2]) : Im(c[p/2])
        #pragma unroll
        for (int i = 0; i < 4; ++i) {
            int r = tid + 256 * i;
            int m = half_sel ? r : (1024 + r);
            int p; float sgn;
            postmap(m, p, sgn);
            float2 cc = X[p >> 1];
            float v = (p & 1) ? cc.y : cc.x;
            float wv = window[m] * sgn * (1.0f / 512.0f);
            float contrib = wv * v;
            if (half_sel == 0) acc[i] = contrib;
            else               acc[i] += contrib;
        }
        __syncthreads();  // X reused next iteration
    }

    // Coalesced store of the 1024 outputs of chunk (b,q).
    size_t base = (size_t)b * OUTB + (size_t)q * 1024 + tid;
    #pragma unroll
    for (int i = 0; i < 4; ++i) {
        out[base + 256 * i] = acc[i];
    }
}

extern "C" void kernel_launch(void* const* d_in, const int* in_sizes, int n_in,
                              void* d_out, int out_size, void* d_ws, size_t ws_size,
                              hipStream_t stream) {
    const float* signal = (const float*)d_in[0];
    const float* window = (const float*)d_in[1];
    float* out = (float*)d_out;
    // 32 batches x 1023 output chunks
    imdct_kernel<<<dim3(32 * CHUNKS), dim3(256), 0, stream>>>(signal, window, out);
}

// Round 2
// 278.970 us; speedup vs baseline: 1.3559x; 1.3559x over previous
//
#include <hip/hip_runtime.h>

// FastIMDCT4: B=32, T=1024, n_fft=2048, hop=1024.
// out[b, q*1024+r] = frames[b,q,1024+r] + frames[b,q+1,r], q in [0,1023)
// frames[m] = sign[m]*window[m]/512 * inter[post[m]];  inter from 512-pt FFT.
//
// R2: one wave per chunk. 512-pt FFT fully in registers:
//   512 = 8 (radix-8 in regs) x 64 (cross-lane radix-2 DIT via shfl_xor).
// LDS only for the final spectrum (split Re/Im planes) + post[] gather.
// No __syncthreads anywhere (per-wave-private LDS regions).

#define CHUNKS 1023

__device__ __forceinline__ float2 cmul(float2 a, float2 b) {
    return make_float2(a.x * b.x - a.y * b.y, a.x * b.y + a.y * b.x);
}
__device__ __forceinline__ float2 cadd(float2 a, float2 b) {
    return make_float2(a.x + b.x, a.y + b.y);
}
__device__ __forceinline__ float2 csub(float2 a, float2 b) {
    return make_float2(a.x - b.x, a.y - b.y);
}
// (cos,sin) of 2*pi*rev  — v_cos_f32/v_sin_f32 take revolutions. |rev| < 1 here.
__device__ __forceinline__ float2 twid(float rev) {
    return make_float2(__builtin_amdgcn_cosf(rev), __builtin_amdgcn_sinf(rev));
}

// post[] / sign[] closed forms (verified in R1: absmax 9.8e-4):
__device__ __forceinline__ void postmap(int m, int& p, float& sgn) {
    bool even = ((m & 1) == 0);
    if (m < 512)       p = even ? (m + 512)  : (512 - m);
    else if (m < 1536) p = even ? (m - 511)  : (1535 - m);
    else               p = even ? (m - 1536) : (2560 - m);
    float s1 = even ? 1.0f : -1.0f;
    sgn = (m < 1536) ? s1 : -s1;
}

__device__ __forceinline__ int brev3(int r) {
    return ((r & 1) << 2) | (r & 2) | ((r >> 2) & 1);
}

// Compute frame FFT for one row; write split planes: planes[0..512)=Re, [512..1024)=Im.
__device__ __forceinline__ void fft_frame(const float* __restrict__ row, int lane,
                                          float* __restrict__ planes) {
    const float2* row2 = (const float2*)row;
    const int rlane = (int)(__brev((unsigned)lane) >> 26);  // brev6(lane)

    // Load: reg r holds sample pair at k = 64*r + rlane (bit-reversed n2 across lanes).
    float2 v[8];
    #pragma unroll
    for (int r = 0; r < 8; ++r) v[r] = row2[64 * r + rlane];

    // c[r] = tw[k] * (row[2k] + i*row[1023-2k]); the imag element lives in
    // lane^63's v[7-r].y (since 511-k = 64*(7-r) + brev6(lane^63)).
    float2 c[8];
    #pragma unroll
    for (int r = 0; r < 8; ++r) {
        float im = __shfl_xor(v[7 - r].y, 63);
        int k = 64 * r + rlane;
        float rev = -((float)k + 0.125f) * (1.0f / 2048.0f);
        c[r] = cmul(twid(rev), make_float2(v[r].x, im));
    }

    // ---- radix-8 DIF in registers (natural in, bitrev3 out) ----
    const float RH = 0.70710678118654752f;
    {   // stage 1 (half=4)
        float2 u0 = c[0], u1 = c[1], u2 = c[2], u3 = c[3];
        float2 l0 = c[4], l1 = c[5], l2 = c[6], l3 = c[7];
        float2 t1 = csub(u1, l1), t2 = csub(u2, l2), t3 = csub(u3, l3);
        c[0] = cadd(u0, l0); c[4] = csub(u0, l0);
        c[1] = cadd(u1, l1); c[5] = cmul(make_float2(RH, -RH), t1);
        c[2] = cadd(u2, l2); c[6] = make_float2(t2.y, -t2.x);           // * -i
        c[3] = cadd(u3, l3); c[7] = cmul(make_float2(-RH, -RH), t3);
    }
    #pragma unroll
    for (int b = 0; b < 8; b += 4) {  // stage 2 (half=2)
        float2 u0 = c[b], u1 = c[b + 1], d0 = c[b + 2], d1 = c[b + 3];
        float2 t = csub(u1, d1);
        c[b] = cadd(u0, d0);
        c[b + 2] = csub(u0, d0);
        c[b + 1] = cadd(u1, d1);
        c[b + 3] = make_float2(t.y, -t.x);                              // * -i
    }
    #pragma unroll
    for (int b = 0; b < 8; b += 2) {  // stage 3 (half=1)
        float2 u = c[b], d = c[b + 1];
        c[b] = cadd(u, d); c[b + 1] = csub(u, d);
    }

    // ---- mid twiddle: reg r holds y[k1=brev3(r)]; z = y * W512^{n2*k1}, n2=rlane ----
    #pragma unroll
    for (int r = 1; r < 8; ++r) {
        int k1 = brev3(r);
        float rev = -(float)(rlane * k1) * (1.0f / 512.0f);
        c[r] = cmul(twid(rev), c[r]);
    }

    // ---- cross-lane 64-pt radix-2 DIT (input bitrev across lanes, natural out) ----
    #pragma unroll
    for (int s = 1; s <= 6; ++s) {
        const int half = 1 << (s - 1);
        const bool hi = (lane & half) != 0;
        float rev = -(float)(lane & (half - 1)) / (float)(1 << s);
        float2 w = twid(rev);
        #pragma unroll
        for (int r = 0; r < 8; ++r) {
            float ox = __shfl_xor(c[r].x, half);
            float oy = __shfl_xor(c[r].y, half);
            float2 oth = make_float2(ox, oy);
            if (s == 1) {
                c[r] = hi ? csub(oth, c[r]) : cadd(c[r], oth);
            } else {
                float2 t = cmul(w, hi ? c[r] : oth);
                c[r] = hi ? csub(oth, t) : cadd(c[r], t);
            }
        }
    }

    // ---- post twiddle + reorder to natural k = j + 8*lane; store split planes ----
    float2 d[8];
    #pragma unroll
    for (int j = 0; j < 8; ++j) {
        int r = brev3(j);  // involution: reg holding y-slot k1=j
        int k = j + 8 * lane;
        float rev = -((float)k + 0.125f) * (1.0f / 2048.0f);
        d[j] = cmul(twid(rev), c[r]);
    }
    float4 r0 = make_float4(d[0].x, d[1].x, d[2].x, d[3].x);
    float4 r1 = make_float4(d[4].x, d[5].x, d[6].x, d[7].x);
    float4 i0 = make_float4(d[0].y, d[1].y, d[2].y, d[3].y);
    float4 i1 = make_float4(d[4].y, d[5].y, d[6].y, d[7].y);
    *(float4*)(planes + 8 * lane)           = r0;
    *(float4*)(planes + 8 * lane + 4)       = r1;
    *(float4*)(planes + 512 + 8 * lane)     = i0;
    *(float4*)(planes + 512 + 8 * lane + 4) = i1;
}

__global__ __launch_bounds__(256) void imdct_kernel(
        const float* __restrict__ signal,
        const float* __restrict__ window,
        float* __restrict__ out) {
    __shared__ float lds[4][2][2 * 512];  // [wave][frame][plane*512]

    const int tid = threadIdx.x;
    const int lane = tid & 63;
    const int w = tid >> 6;

    // XCD swizzle: 8184 blocks = 8 XCDs x 1023; consecutive chunks share an XCD's L2.
    const int bid = blockIdx.x;
    const int nb = (bid & 7) * 1023 + (bid >> 3);
    const int chunk = nb * 4 + w;               // [0, 32736)
    const int b = chunk / CHUNKS;
    const int q = chunk - b * CHUNKS;

    const float* base = signal + (size_t)(b * 1024 + q) * 1024;
    fft_frame(base,        lane, &lds[w][0][0]);   // frame q
    fft_frame(base + 1024, lane, &lds[w][1][0]);   // frame q+1

    const float* f0 = &lds[w][0][0];
    const float* f1 = &lds[w][1][0];
    float* orow = out + (size_t)b * (CHUNKS * 1024) + (size_t)q * 1024;

    #pragma unroll
    for (int it = 0; it < 4; ++it) {
        const int rbase = 256 * it + 4 * lane;
        float4 w_hi = *(const float4*)(window + 1024 + rbase);
        float4 w_lo = *(const float4*)(window + rbase);
        const float* whp = &w_hi.x;
        const float* wlp = &w_lo.x;
        float4 o;
        float* op = &o.x;
        #pragma unroll
        for (int e = 0; e < 4; ++e) {
            int r = rbase + e;
            int p0; float s0; postmap(1024 + r, p0, s0);   // frame q contribution
            int p1; float s1; postmap(r, p1, s1);          // frame q+1 contribution
            float v0 = f0[(p0 & 1) * 512 + (p0 >> 1)];
            float v1 = f1[(p1 & 1) * 512 + (p1 >> 1)];
            op[e] = (s0 * whp[e] * v0 + s1 * wlp[e] * v1) * (1.0f / 512.0f);
        }
        *(float4*)(orow + rbase) = o;
    }
}

extern "C" void kernel_launch(void* const* d_in, const int* in_sizes, int n_in,
                              void* d_out, int out_size, void* d_ws, size_t ws_size,
                              hipStream_t stream) {
    const float* signal = (const float*)d_in[0];
    const float* window = (const float*)d_in[1];
    float* out = (float*)d_out;
    // 32 batches x 1023 chunks, 4 chunks (waves) per block
    imdct_kernel<<<dim3(32 * CHUNKS / 4), dim3(256), 0, stream>>>(signal, window, out);
}

// Round 3
// 238.818 us; speedup vs baseline: 1.5838x; 1.1681x over previous
//
#include <hip/hip_runtime.h>

// FastIMDCT4: B=32, T=1024, n_fft=2048, hop=1024.
// out[b, q*1024+r] = frames[b,q,1024+r] + frames[b,q+1,r], q in [0,1023)
// frames[m] = sign[m]*window[m]/512 * inter[post[m]];  inter from 512-pt FFT.
//
// R3: 8-wave blocks. Each block covers 7 chunks, computes 8 frames (one
// register-resident 512-pt FFT per wave: radix-8 in regs x 64-pt cross-lane
// via shfl_xor) into LDS, one barrier, then cooperative extraction.
// FFT work per chunk: 8/7 (was 2.0 in R2).

#define CHUNKS 1023
#define CPB 7            // chunks per block
#define BPB 147          // blocks per batch: ceil(1023/7)

__device__ __forceinline__ float2 cmul(float2 a, float2 b) {
    return make_float2(a.x * b.x - a.y * b.y, a.x * b.y + a.y * b.x);
}
__device__ __forceinline__ float2 cadd(float2 a, float2 b) {
    return make_float2(a.x + b.x, a.y + b.y);
}
__device__ __forceinline__ float2 csub(float2 a, float2 b) {
    return make_float2(a.x - b.x, a.y - b.y);
}
// (cos,sin) of 2*pi*rev  — v_cos_f32/v_sin_f32 take revolutions; |rev| < 1 here.
__device__ __forceinline__ float2 twid(float rev) {
    return make_float2(__builtin_amdgcn_cosf(rev), __builtin_amdgcn_sinf(rev));
}

// post[] / sign[] closed forms (verified R1/R2: absmax 9.8e-4):
__device__ __forceinline__ void postmap(int m, int& p, float& sgn) {
    bool even = ((m & 1) == 0);
    if (m < 512)       p = even ? (m + 512)  : (512 - m);
    else if (m < 1536) p = even ? (m - 511)  : (1535 - m);
    else               p = even ? (m - 1536) : (2560 - m);
    float s1 = even ? 1.0f : -1.0f;
    sgn = (m < 1536) ? s1 : -s1;
}

__device__ __forceinline__ int brev3(int r) {
    return ((r & 1) << 2) | (r & 2) | ((r >> 2) & 1);
}

// 512-pt FFT of one frame; writes split planes: planes[0..512)=Re, [512..1024)=Im.
__device__ __forceinline__ void fft_frame(const float* __restrict__ row, int lane,
                                          float* __restrict__ planes) {
    const float2* row2 = (const float2*)row;
    const int rlane = (int)(__brev((unsigned)lane) >> 26);  // brev6(lane)

    // Load: reg r holds sample pair at k = 64*r + rlane (bit-reversed n2 across lanes).
    float2 v[8];
    #pragma unroll
    for (int r = 0; r < 8; ++r) v[r] = row2[64 * r + rlane];

    // c[r] = tw[k] * (row[2k] + i*row[1023-2k]); imag element lives in
    // lane^63's v[7-r].y (511-k = 64*(7-r) + brev6(lane^63)).
    float2 c[8];
    #pragma unroll
    for (int r = 0; r < 8; ++r) {
        float im = __shfl_xor(v[7 - r].y, 63);
        int k = 64 * r + rlane;
        float rev = -((float)k + 0.125f) * (1.0f / 2048.0f);
        c[r] = cmul(twid(rev), make_float2(v[r].x, im));
    }

    // ---- radix-8 DIF in registers (natural in, bitrev3 out) ----
    const float RH = 0.70710678118654752f;
    {   // stage 1 (half=4)
        float2 u0 = c[0], u1 = c[1], u2 = c[2], u3 = c[3];
        float2 l0 = c[4], l1 = c[5], l2 = c[6], l3 = c[7];
        float2 t1 = csub(u1, l1), t2 = csub(u2, l2), t3 = csub(u3, l3);
        c[0] = cadd(u0, l0); c[4] = csub(u0, l0);
        c[1] = cadd(u1, l1); c[5] = cmul(make_float2(RH, -RH), t1);
        c[2] = cadd(u2, l2); c[6] = make_float2(t2.y, -t2.x);           // * -i
        c[3] = cadd(u3, l3); c[7] = cmul(make_float2(-RH, -RH), t3);
    }
    #pragma unroll
    for (int b = 0; b < 8; b += 4) {  // stage 2 (half=2)
        float2 u0 = c[b], u1 = c[b + 1], d0 = c[b + 2], d1 = c[b + 3];
        float2 t = csub(u1, d1);
        c[b] = cadd(u0, d0);
        c[b + 2] = csub(u0, d0);
        c[b + 1] = cadd(u1, d1);
        c[b + 3] = make_float2(t.y, -t.x);                              // * -i
    }
    #pragma unroll
    for (int b = 0; b < 8; b += 2) {  // stage 3 (half=1)
        float2 u = c[b], d = c[b + 1];
        c[b] = cadd(u, d); c[b + 1] = csub(u, d);
    }

    // ---- mid twiddle: reg r holds y[k1=brev3(r)]; z = y * W512^{n2*k1}, n2=rlane ----
    #pragma unroll
    for (int r = 1; r < 8; ++r) {
        int k1 = brev3(r);
        float rev = -(float)(rlane * k1) * (1.0f / 512.0f);
        c[r] = cmul(twid(rev), c[r]);
    }

    // ---- cross-lane 64-pt radix-2 DIT (input bitrev across lanes, natural out) ----
    #pragma unroll
    for (int s = 1; s <= 6; ++s) {
        const int half = 1 << (s - 1);
        const bool hi = (lane & half) != 0;
        float rev = -(float)(lane & (half - 1)) / (float)(1 << s);
        float2 w = twid(rev);
        #pragma unroll
        for (int r = 0; r < 8; ++r) {
            float ox = __shfl_xor(c[r].x, half);
            float oy = __shfl_xor(c[r].y, half);
            float2 oth = make_float2(ox, oy);
            if (s == 1) {
                c[r] = hi ? csub(oth, c[r]) : cadd(c[r], oth);
            } else {
                float2 t = cmul(w, hi ? c[r] : oth);
                c[r] = hi ? csub(oth, t) : cadd(c[r], t);
            }
        }
    }

    // ---- post twiddle + reorder to natural k = j + 8*lane; store split planes ----
    float2 d[8];
    #pragma unroll
    for (int j = 0; j < 8; ++j) {
        int r = brev3(j);  // involution: reg holding y-slot k1=j
        int k = j + 8 * lane;
        float rev = -((float)k + 0.125f) * (1.0f / 2048.0f);
        d[j] = cmul(twid(rev), c[r]);
    }
    float4 r0 = make_float4(d[0].x, d[1].x, d[2].x, d[3].x);
    float4 r1 = make_float4(d[4].x, d[5].x, d[6].x, d[7].x);
    float4 i0 = make_float4(d[0].y, d[1].y, d[2].y, d[3].y);
    float4 i1 = make_float4(d[4].y, d[5].y, d[6].y, d[7].y);
    *(float4*)(planes + 8 * lane)           = r0;
    *(float4*)(planes + 8 * lane + 4)       = r1;
    *(float4*)(planes + 512 + 8 * lane)     = i0;
    *(float4*)(planes + 512 + 8 * lane + 4) = i1;
}

__global__ __launch_bounds__(512) void imdct_kernel(
        const float* __restrict__ signal,
        const float* __restrict__ window,
        float* __restrict__ out) {
    __shared__ float lds[8][1024];  // 8 frames x (Re[512] | Im[512]) = 32 KB

    const int tid = threadIdx.x;
    const int lane = tid & 63;
    const int w = tid >> 6;

    const int bid = blockIdx.x;
    const int b = bid / BPB;
    const int cblk = bid - b * BPB;
    const int q0 = cblk * CPB;          // first chunk of this block

    // Phase 1: each wave FFTs one frame (q0+w) into its LDS slot.
    const int f = q0 + w;
    if (f <= 1023) {
        fft_frame(signal + (size_t)(b * 1024 + f) * 1024, lane, &lds[w][0]);
    }
    __syncthreads();

    // Phase 2: cooperative extraction for the 7 chunks.
    float* orow_base = out + (size_t)b * (CHUNKS * 1024);
    const int r = 2 * tid;               // element pair within a chunk

    #pragma unroll
    for (int j = 0; j < CPB; ++j) {
        const int qj = q0 + j;
        if (qj > 1022) break;            // block-uniform
        const float* f0 = &lds[j][0];
        const float* f1 = &lds[j + 1][0];
        float2 wh = *(const float2*)(window + 1024 + r);
        float2 wl = *(const float2*)(window + r);
        const float* whp = &wh.x;
        const float* wlp = &wl.x;
        float2 o;
        float* op = &o.x;
        #pragma unroll
        for (int e = 0; e < 2; ++e) {
            int p0; float s0; postmap(1024 + r + e, p0, s0);   // frame qj
            int p1; float s1; postmap(r + e, p1, s1);          // frame qj+1
            float v0 = f0[(p0 & 1) * 512 + (p0 >> 1)];
            float v1 = f1[(p1 & 1) * 512 + (p1 >> 1)];
            op[e] = (s0 * whp[e] * v0 + s1 * wlp[e] * v1) * (1.0f / 512.0f);
        }
        *(float2*)(orow_base + (size_t)qj * 1024 + r) = o;
    }
}

extern "C" void kernel_launch(void* const* d_in, const int* in_sizes, int n_in,
                              void* d_out, int out_size, void* d_ws, size_t ws_size,
                              hipStream_t stream) {
    const float* signal = (const float*)d_in[0];
    const float* window = (const float*)d_in[1];
    float* out = (float*)d_out;
    // 32 batches x 147 blocks (7 chunks each), 512 threads (8 waves) per block
    imdct_kernel<<<dim3(32 * BPB), dim3(512), 0, stream>>>(signal, window, out);
}